// Round 6
// baseline (93.036 us; speedup 1.0000x reference)
//
#include <hip/hip_runtime.h>
#include <cstddef>

typedef __attribute__((ext_vector_type(8))) short short8;
typedef __attribute__((ext_vector_type(16))) float f32x16;

#define NB 4
#define NSEQ 6400
#define CDIM 48
#define DHEAD 16
#define WSZ 800
#define NWIN 8
#define INNER 64
#define NROWS 25600
#define NWH 256                       // 2*NB*NWIN*NHEADS window-heads
#define SCHUNK (WSZ * DHEAD)          // 12800
#define CHUNK (3 * SCHUNK)            // 38400 bf16 per (e,b,w,h)
#define QKV_TOTAL (NWH * CHUNK)
#define AO_PER (NROWS * INNER)

#define LOG2E 1.4426950408889634f
#define C0EXP (-8.0f * LOG2E)

static __device__ __forceinline__ uint pkbf(float a, float b) {
  uint r;
  asm("v_cvt_pk_bf16_f32 %0, %1, %2" : "=v"(r) : "v"(a), "v"(b));
  return r;
}

// ---------------------------------------------------------------------------
// Kernel 1: QKV projection via MFMA, C^T formulation (D[o][row]).
// W staged ONCE per block into LDS in fragment order (bf16, Q-scale folded):
// 18 fragments = 6 mtiles x 3 ksteps (FIX: was sized/staged for 9 -> OOB
// reads for the mh=1 waves -> NaN).  Per-wave W access = 9 conflict-free
// ds_read_b128; x B-frags direct from global; stores packed uint2.
// ---------------------------------------------------------------------------
__global__ __launch_bounds__(256) void qkv_mfma(const float* __restrict__ x1,
                                                const float* __restrict__ x2,
                                                const float* __restrict__ Wqkv,
                                                ushort* __restrict__ wsq) {
  const int tid = threadIdx.x;
  const int lane = tid & 63;
  const int wv = tid >> 6;

  __shared__ __align__(16) ushort Wl[18 * 64 * 8];   // 18.4 KB, frag order

  // stage W -> LDS: slot = (mt*3+ks)*64 + lane2, each a short8; 1152 slots
  for (int slot = tid; slot < 1152; slot += 256) {
    const int mtks = slot >> 6, l2 = slot & 63;
    const int mt = mtks / 3, ks = mtks % 3;
    const int o = mt * 32 + (l2 & 31);
    const int c0 = ks * 16 + (l2 >> 5) * 8;
    const float sc = ((o % CDIM) < DHEAD) ? 0.25f : 1.0f;   // fold attn scale
    const float4* p = reinterpret_cast<const float4*>(Wqkv + (size_t)o * CDIM + c0);
    float4 u = p[0], v = p[1];
    union { uint q[4]; short8 s; } t;
    t.q[0] = pkbf(u.x * sc, u.y * sc); t.q[1] = pkbf(u.z * sc, u.w * sc);
    t.q[2] = pkbf(v.x * sc, v.y * sc); t.q[3] = pkbf(v.z * sc, v.w * sc);
    *reinterpret_cast<short8*>(Wl + (size_t)slot * 8) = t.s;
  }
  __syncthreads();

  const int task = blockIdx.x * 4 + wv;   // [0,3200)
  const int batch = task >> 1;            // 32-row batch  [0,1600)
  const int mh = task & 1;                // output half: mtiles mh*3..+3
  const int e = batch / 800;
  const int rb = (batch % 800) * 32;
  const float* __restrict__ x = e ? x2 : x1;

  const int rl = lane & 31;
  const int lg = lane >> 5;
  const int row = rb + rl;

  // B-frags: x[row][c0..c0+8) -> bf16
  short8 bf[3];
#pragma unroll
  for (int ks = 0; ks < 3; ++ks) {
    const float4* p =
        reinterpret_cast<const float4*>(x + (size_t)row * CDIM + ks * 16 + lg * 8);
    float4 u = p[0], v = p[1];
    union { uint q[4]; short8 s; } t;
    t.q[0] = pkbf(u.x, u.y); t.q[1] = pkbf(u.z, u.w);
    t.q[2] = pkbf(v.x, v.y); t.q[3] = pkbf(v.z, v.w);
    bf[ks] = t.s;
  }

  const int b = rb / NSEQ;
  const int i0 = rb % NSEQ;
  const int wi = i0 / WSZ;
  const int iw = (i0 % WSZ) + rl;
  const int whb = ((e * NB + b) * NWIN + wi) * 4;   // + h later

#pragma unroll
  for (int mt = mh * 3; mt < mh * 3 + 3; ++mt) {
    const int obase = mt * 32;
    short8 wf0 = *reinterpret_cast<const short8*>(Wl + ((mt * 3 + 0) * 64 + lane) * 8);
    short8 wf1 = *reinterpret_cast<const short8*>(Wl + ((mt * 3 + 1) * 64 + lane) * 8);
    short8 wf2 = *reinterpret_cast<const short8*>(Wl + ((mt * 3 + 2) * 64 + lane) * 8);

    f32x16 acc;
#pragma unroll
    for (int r = 0; r < 16; ++r) acc[r] = 0.f;
    acc = __builtin_amdgcn_mfma_f32_32x32x16_bf16(wf0, bf[0], acc, 0, 0, 0);
    acc = __builtin_amdgcn_mfma_f32_32x32x16_bf16(wf1, bf[1], acc, 0, 0, 0);
    acc = __builtin_amdgcn_mfma_f32_32x32x16_bf16(wf2, bf[2], acc, 0, 0, 0);

    // D: o' = obase + (r&3)+8*(r>>2)+4*lg, row' = rb+(lane&31)
#pragma unroll
    for (int q = 0; q < 4; ++q) {
      const int ob = obase + q * 8 + 4 * lg;
      const int g = ob >> 4;
      const int h = g / 3, s = g % 3, d0 = ob & 15;
      uint2 pk;
      pk.x = pkbf(acc[4 * q + 0], acc[4 * q + 1]);
      pk.y = pkbf(acc[4 * q + 2], acc[4 * q + 3]);
      *reinterpret_cast<uint2*>(wsq + (size_t)(whb + h) * CHUNK + s * SCHUNK +
                                iw * DHEAD + d0) = pk;
    }
  }
}

// ---------------------------------------------------------------------------
// Kernel 2: MFMA windowed attention, j-tiled double-buffered LDS.
// (fused fma+exp2 softmax, V-frag reads hoisted, setprio around PV MFMAs)
// ---------------------------------------------------------------------------
#define JC 160
#define NCH 5
#define KSL (5 * 64 * 8)
#define VROW 168
#define VSL (17 * VROW)

__global__ __launch_bounds__(320) void attn_mfma(const ushort* __restrict__ wsq,
                                                 float* __restrict__ ao) {
  const int tid = threadIdx.x;
  const int lane = tid & 63;
  const int wv = tid >> 6;
  const int bid = blockIdx.x;
  const int wh = bid & (NWH - 1);
  const int sub = bid >> 8;
  const int qtile = sub * 5 + wv;        // 0..24

  const ushort* __restrict__ Qg = wsq + (size_t)wh * CHUNK;
  const ushort* __restrict__ Kg = Qg + SCHUNK;
  const ushort* __restrict__ Vg = Kg + SCHUNK;

  __shared__ __align__(16) ushort Ks[2][KSL];
  __shared__ __align__(16) ushort Vs[2][VSL];

  const int kj = (tid >> 6) * 32 + (tid & 31);
  const int khalf = (tid >> 5) & 1;
  const int vj = tid % 160;
  const int vhalf = tid / 160;

  short8 kreg = *reinterpret_cast<const short8*>(Kg + (size_t)kj * DHEAD + khalf * 8);
  short8 vreg = *reinterpret_cast<const short8*>(Vg + (size_t)vj * DHEAD + vhalf * 8);

  if (tid < JC) {
    Vs[0][16 * VROW + tid] = 0x3F80;
    Vs[1][16 * VROW + tid] = 0x3F80;
  }

  *reinterpret_cast<short8*>(&Ks[0][tid * 8]) = kreg;
#pragma unroll
  for (int u = 0; u < 8; ++u)
    Vs[0][(vhalf * 8 + u) * VROW + vj] = (ushort)vreg[u];

  kreg = *reinterpret_cast<const short8*>(Kg + (size_t)(JC + kj) * DHEAD + khalf * 8);
  vreg = *reinterpret_cast<const short8*>(Vg + (size_t)(JC + vj) * DHEAD + vhalf * 8);

  short8 qf = *reinterpret_cast<const short8*>(
      Qg + (size_t)(qtile * 32 + (lane & 31)) * DHEAD + (lane >> 5) * 8);

  __syncthreads();

  f32x16 zacc;
#pragma unroll
  for (int r = 0; r < 16; ++r) zacc[r] = 0.f;
  f32x16 accO = zacc;

  const int n31 = lane & 31;
  const int lg = lane >> 5;
  const int vrow = (n31 <= 16) ? n31 : (n31 & 15);   // col 16 -> ones row

  for (int ch = 0; ch < NCH; ++ch) {
    const ushort* __restrict__ Kc = Ks[ch & 1];
    const ushort* __restrict__ Vc = Vs[ch & 1];
#pragma unroll
    for (int jl = 0; jl < 5; ++jl) {
      short8 kf = *reinterpret_cast<const short8*>(Kc + (jl * 64 + lane) * 8);
      // V B-frags: independent of P -- issue early
      short8 vf0 = *reinterpret_cast<const short8*>(Vc + vrow * VROW + jl * 32 + lg * 8);
      short8 vf1 = *reinterpret_cast<const short8*>(Vc + vrow * VROW + jl * 32 + 16 + lg * 8);

      f32x16 st = __builtin_amdgcn_mfma_f32_32x32x16_bf16(kf, qf, zacc, 0, 0, 0);

      float p[16];
#pragma unroll
      for (int r = 0; r < 16; ++r)
        p[r] = exp2f(fmaf(st[r], LOG2E, C0EXP));   // exp(st-8), 2 VALU ops

      uint x0, x1, y0, y1;
      asm("v_cvt_pk_bf16_f32 %0, %1, %2" : "=v"(x0) : "v"(p[0]), "v"(p[1]));
      asm("v_cvt_pk_bf16_f32 %0, %1, %2" : "=v"(x1) : "v"(p[2]), "v"(p[3]));
      asm("v_cvt_pk_bf16_f32 %0, %1, %2" : "=v"(y0) : "v"(p[4]), "v"(p[5]));
      asm("v_cvt_pk_bf16_f32 %0, %1, %2" : "=v"(y1) : "v"(p[6]), "v"(p[7]));
      asm("v_permlane32_swap_b32 %0, %1" : "+v"(x0), "+v"(y0));
      asm("v_permlane32_swap_b32 %0, %1" : "+v"(x1), "+v"(y1));
      union { uint u[4]; short8 s; } pa0;
      pa0.u[0] = x0; pa0.u[1] = x1; pa0.u[2] = y0; pa0.u[3] = y1;

      uint z0, z1, w0, w1;
      asm("v_cvt_pk_bf16_f32 %0, %1, %2" : "=v"(z0) : "v"(p[8]), "v"(p[9]));
      asm("v_cvt_pk_bf16_f32 %0, %1, %2" : "=v"(z1) : "v"(p[10]), "v"(p[11]));
      asm("v_cvt_pk_bf16_f32 %0, %1, %2" : "=v"(w0) : "v"(p[12]), "v"(p[13]));
      asm("v_cvt_pk_bf16_f32 %0, %1, %2" : "=v"(w1) : "v"(p[14]), "v"(p[15]));
      asm("v_permlane32_swap_b32 %0, %1" : "+v"(z0), "+v"(w0));
      asm("v_permlane32_swap_b32 %0, %1" : "+v"(z1), "+v"(w1));
      union { uint u[4]; short8 s; } pa1;
      pa1.u[0] = z0; pa1.u[1] = z1; pa1.u[2] = w0; pa1.u[3] = w1;

      __builtin_amdgcn_s_setprio(1);
      accO = __builtin_amdgcn_mfma_f32_32x32x16_bf16(pa0.s, vf0, accO, 0, 0, 0);
      accO = __builtin_amdgcn_mfma_f32_32x32x16_bf16(pa1.s, vf1, accO, 0, 0, 0);
      __builtin_amdgcn_s_setprio(0);
    }
    if (ch + 1 < NCH) {
      __syncthreads();
      const int nxt = (ch + 1) & 1;
      *reinterpret_cast<short8*>(&Ks[nxt][tid * 8]) = kreg;
#pragma unroll
      for (int u = 0; u < 8; ++u)
        Vs[nxt][(vhalf * 8 + u) * VROW + vj] = (ushort)vreg[u];
      if (ch + 2 < NCH) {
        kreg = *reinterpret_cast<const short8*>(
            Kg + (size_t)((ch + 2) * JC + kj) * DHEAD + khalf * 8);
        vreg = *reinterpret_cast<const short8*>(
            Vg + (size_t)((ch + 2) * JC + vj) * DHEAD + vhalf * 8);
      }
      __syncthreads();
    }
  }

  const int h = wh & 3;
  const int w = (wh >> 2) & 7;
  const int b = (wh >> 5) & 3;
  const int e = wh >> 7;
  const size_t rowbase =
      (size_t)e * NROWS + (size_t)b * NSEQ + (size_t)w * WSZ + (size_t)qtile * 32;
  const int src = 16 + 32 * lg;

#pragma unroll
  for (int r = 0; r < 16; ++r) {
    float den = __shfl(accO[r], src);
    if (n31 < 16) {
      int i = (r & 3) + 8 * (r >> 2) + 4 * lg;
      ao[(rowbase + i) * INNER + h * DHEAD + n31] =
          accO[r] * __builtin_amdgcn_rcpf(den);
    }
  }
}

// ---------------------------------------------------------------------------
// Kernel 3: out = (ao1 + ao2) @ Wout^T + 2*bout.  LDS-staged: coalesced
// float4 global reads; broadcast LDS reads (per-rq k-rotation -> the 4
// row-groups hit disjoint banks).  400 blocks x 192 threads, 64 rows each.
// ---------------------------------------------------------------------------
#define OSTR 76                        // row stride in floats (304 B = 19*16)
__global__ __launch_bounds__(192) void out_proj(const float* __restrict__ ao_all,
                                                const float* __restrict__ Wout,
                                                const float* __restrict__ bout,
                                                float* __restrict__ out) {
  const int tid = threadIdx.x;
  const int row0 = blockIdx.x * 64;

  __shared__ float aos[64 * OSTR];     // 19.5 KB

  const float4* __restrict__ a14 = reinterpret_cast<const float4*>(ao_all);
  const float4* __restrict__ a24 = a14 + (size_t)NROWS * (INNER / 4);

  for (int idx = tid; idx < 64 * 16; idx += 192) {
    const int r = idx >> 4, k4 = idx & 15;
    float4 u = a14[(size_t)(row0 + r) * 16 + k4];
    float4 v = a24[(size_t)(row0 + r) * 16 + k4];
    float4 s;
    s.x = u.x + v.x; s.y = u.y + v.y; s.z = u.z + v.z; s.w = u.w + v.w;
    *reinterpret_cast<float4*>(aos + r * OSTR + k4 * 4) = s;
  }

  const int j = tid % 48;
  const int rq = tid / 48;             // 0..3

  float wreg[INNER];
#pragma unroll
  for (int k4 = 0; k4 < 16; ++k4) {
    float4 wv4 = reinterpret_cast<const float4*>(Wout + (size_t)j * INNER)[k4];
    wreg[k4 * 4 + 0] = wv4.x; wreg[k4 * 4 + 1] = wv4.y;
    wreg[k4 * 4 + 2] = wv4.z; wreg[k4 * 4 + 3] = wv4.w;
  }
  const float bj = 2.0f * bout[j];

  __syncthreads();

  for (int r16 = 0; r16 < 16; ++r16) {
    const int r = rq * 16 + r16;
    float a0 = 0.f, a1 = 0.f, a2 = 0.f, a3 = 0.f;
#pragma unroll
    for (int kk = 0; kk < 16; ++kk) {
      const int k4 = (kk + rq * 4) & 15;          // bank-disjoint rotation
      float4 av = *reinterpret_cast<const float4*>(aos + r * OSTR + k4 * 4);
      a0 = fmaf(av.x, wreg[k4 * 4 + 0], a0);
      a1 = fmaf(av.y, wreg[k4 * 4 + 1], a1);
      a2 = fmaf(av.z, wreg[k4 * 4 + 2], a2);
      a3 = fmaf(av.w, wreg[k4 * 4 + 3], a3);
    }
    out[(size_t)(row0 + r) * CDIM + j] = (a0 + a1) + (a2 + a3) + bj;
  }
}

// ---------------------------------------------------------------------------
extern "C" void kernel_launch(void* const* d_in, const int* in_sizes, int n_in,
                              void* d_out, int out_size, void* d_ws,
                              size_t ws_size, hipStream_t stream) {
  const float* x1 = (const float*)d_in[0];
  const float* x2 = (const float*)d_in[1];
  const float* Wqkv = (const float*)d_in[2];
  const float* Wout = (const float*)d_in[3];
  const float* bout = (const float*)d_in[4];
  float* out = (float*)d_out;
  ushort* wsq = (ushort*)d_ws;
  float* ao = (float*)(wsq + QKV_TOTAL);

  qkv_mfma<<<dim3(800), dim3(256), 0, stream>>>(x1, x2, Wqkv, wsq);
  attn_mfma<<<dim3(1280), dim3(320), 0, stream>>>(wsq, ao);
  out_proj<<<dim3(400), dim3(192), 0, stream>>>(ao, Wout, bout, out);
}

// Round 7
// 92.390 us; speedup vs baseline: 1.0070x; 1.0070x over previous
//
#include <hip/hip_runtime.h>
#include <cstddef>

typedef __attribute__((ext_vector_type(8))) short short8;
typedef __attribute__((ext_vector_type(16))) float f32x16;

#define NB 4
#define NSEQ 6400
#define CDIM 48
#define DHEAD 16
#define WSZ 800
#define NWIN 8
#define INNER 64
#define NROWS 25600
#define NWH 256                       // 2*NB*NWIN*NHEADS window-heads
#define SCHUNK (WSZ * DHEAD)          // 12800
#define CHUNK (3 * SCHUNK)            // 38400 bf16 per (e,b,w,h)
#define QKV_TOTAL (NWH * CHUNK)
#define AO_PER (NROWS * INNER)

#define LOG2E 1.4426950408889634f
#define C0EXP (-8.0f * LOG2E)

static __device__ __forceinline__ uint pkbf(float a, float b) {
  uint r;
  asm("v_cvt_pk_bf16_f32 %0, %1, %2" : "=v"(r) : "v"(a), "v"(b));
  return r;
}

// ---------------------------------------------------------------------------
// Kernel 1: QKV projection via MFMA, C^T formulation (unchanged from r6).
// ---------------------------------------------------------------------------
__global__ __launch_bounds__(256) void qkv_mfma(const float* __restrict__ x1,
                                                const float* __restrict__ x2,
                                                const float* __restrict__ Wqkv,
                                                ushort* __restrict__ wsq) {
  const int tid = threadIdx.x;
  const int lane = tid & 63;
  const int wv = tid >> 6;

  __shared__ __align__(16) ushort Wl[18 * 64 * 8];   // 18.4 KB, frag order

  for (int slot = tid; slot < 1152; slot += 256) {
    const int mtks = slot >> 6, l2 = slot & 63;
    const int mt = mtks / 3, ks = mtks % 3;
    const int o = mt * 32 + (l2 & 31);
    const int c0 = ks * 16 + (l2 >> 5) * 8;
    const float sc = ((o % CDIM) < DHEAD) ? 0.25f : 1.0f;   // fold attn scale
    const float4* p = reinterpret_cast<const float4*>(Wqkv + (size_t)o * CDIM + c0);
    float4 u = p[0], v = p[1];
    union { uint q[4]; short8 s; } t;
    t.q[0] = pkbf(u.x * sc, u.y * sc); t.q[1] = pkbf(u.z * sc, u.w * sc);
    t.q[2] = pkbf(v.x * sc, v.y * sc); t.q[3] = pkbf(v.z * sc, v.w * sc);
    *reinterpret_cast<short8*>(Wl + (size_t)slot * 8) = t.s;
  }
  __syncthreads();

  const int task = blockIdx.x * 4 + wv;   // [0,3200)
  const int batch = task >> 1;
  const int mh = task & 1;
  const int e = batch / 800;
  const int rb = (batch % 800) * 32;
  const float* __restrict__ x = e ? x2 : x1;

  const int rl = lane & 31;
  const int lg = lane >> 5;
  const int row = rb + rl;

  short8 bf[3];
#pragma unroll
  for (int ks = 0; ks < 3; ++ks) {
    const float4* p =
        reinterpret_cast<const float4*>(x + (size_t)row * CDIM + ks * 16 + lg * 8);
    float4 u = p[0], v = p[1];
    union { uint q[4]; short8 s; } t;
    t.q[0] = pkbf(u.x, u.y); t.q[1] = pkbf(u.z, u.w);
    t.q[2] = pkbf(v.x, v.y); t.q[3] = pkbf(v.z, v.w);
    bf[ks] = t.s;
  }

  const int b = rb / NSEQ;
  const int i0 = rb % NSEQ;
  const int wi = i0 / WSZ;
  const int iw = (i0 % WSZ) + rl;
  const int whb = ((e * NB + b) * NWIN + wi) * 4;

#pragma unroll
  for (int mt = mh * 3; mt < mh * 3 + 3; ++mt) {
    const int obase = mt * 32;
    short8 wf0 = *reinterpret_cast<const short8*>(Wl + ((mt * 3 + 0) * 64 + lane) * 8);
    short8 wf1 = *reinterpret_cast<const short8*>(Wl + ((mt * 3 + 1) * 64 + lane) * 8);
    short8 wf2 = *reinterpret_cast<const short8*>(Wl + ((mt * 3 + 2) * 64 + lane) * 8);

    f32x16 acc;
#pragma unroll
    for (int r = 0; r < 16; ++r) acc[r] = 0.f;
    acc = __builtin_amdgcn_mfma_f32_32x32x16_bf16(wf0, bf[0], acc, 0, 0, 0);
    acc = __builtin_amdgcn_mfma_f32_32x32x16_bf16(wf1, bf[1], acc, 0, 0, 0);
    acc = __builtin_amdgcn_mfma_f32_32x32x16_bf16(wf2, bf[2], acc, 0, 0, 0);

#pragma unroll
    for (int q = 0; q < 4; ++q) {
      const int ob = obase + q * 8 + 4 * lg;
      const int g = ob >> 4;
      const int h = g / 3, s = g % 3, d0 = ob & 15;
      uint2 pk;
      pk.x = pkbf(acc[4 * q + 0], acc[4 * q + 1]);
      pk.y = pkbf(acc[4 * q + 2], acc[4 * q + 3]);
      *reinterpret_cast<uint2*>(wsq + (size_t)(whb + h) * CHUNK + s * SCHUNK +
                                iw * DHEAD + d0) = pk;
    }
  }
}

// ---------------------------------------------------------------------------
// Kernel 2: MFMA windowed attention, barrier-free main loop.
// K-frags read DIRECT from global (wave's frag = one coalesced 1KB segment;
// depth-1 prefetch; L2-shared across the 5 sub-blocks of a wh).  Only V^T
// in LDS (single-staged once, 16 rows x stride 820 = 2-way max aliasing)
// + ones[32] feeding accO col 16 = softmax denominator.  26.3 KB LDS,
// no syncthreads after the first -> waves run free.
// ---------------------------------------------------------------------------
#define VROW 820
__global__ __launch_bounds__(320) void attn_mfma(const ushort* __restrict__ wsq,
                                                 float* __restrict__ ao) {
  const int tid = threadIdx.x;
  const int lane = tid & 63;
  const int wv = tid >> 6;
  const int bid = blockIdx.x;
  const int wh = bid & (NWH - 1);
  const int sub = bid >> 8;
  const int qtile = sub * 5 + wv;        // 0..24

  const ushort* __restrict__ Qg = wsq + (size_t)wh * CHUNK;
  const ushort* __restrict__ Kg = Qg + SCHUNK;
  const ushort* __restrict__ Vg = Kg + SCHUNK;

  __shared__ __align__(16) ushort VTs[16 * VROW];   // 26240 B
  __shared__ __align__(16) ushort ones[32];         // 64 B

  // stage V^T once (scatter transpose; 2-way write aliasing = free)
  const int vj = tid % 160;
  const int vhalf = tid / 160;
#pragma unroll
  for (int c = 0; c < 5; ++c) {
    short8 vv = *reinterpret_cast<const short8*>(
        Vg + (size_t)(c * 160 + vj) * DHEAD + vhalf * 8);
#pragma unroll
    for (int u = 0; u < 8; ++u)
      VTs[(vhalf * 8 + u) * VROW + c * 160 + vj] = (ushort)vv[u];
  }
  if (tid < 32) ones[tid] = 0x3F80;

  // Q B-frag: lane holds Q[qtile*32 + (lane&31)][(lane>>5)*8 ..+8]
  short8 qf = *reinterpret_cast<const short8*>(
      Qg + (size_t)(qtile * 32 + (lane & 31)) * DHEAD + (lane >> 5) * 8);

  const int n31 = lane & 31;
  const int lg = lane >> 5;
  const ushort* __restrict__ vbase =
      (n31 == 16) ? ones : (VTs + (n31 & 15) * VROW);
  const int jstep = (n31 == 16) ? 0 : 32;
  const int vstart = lg * 8;

  __syncthreads();

  f32x16 zacc;
#pragma unroll
  for (int r = 0; r < 16; ++r) zacc[r] = 0.f;
  f32x16 accO = zacc;

  // K frag pointer: wave reads one coalesced 1KB segment per jt
  const ushort* __restrict__ kptr = Kg + (size_t)n31 * DHEAD + lg * 8;
  short8 kf = *reinterpret_cast<const short8*>(kptr);

#pragma unroll 5
  for (int jt = 0; jt < 25; ++jt) {
    short8 kf_n;
    if (jt < 24)
      kf_n = *reinterpret_cast<const short8*>(kptr + (size_t)(jt + 1) * 32 * DHEAD);
    short8 vf0 = *reinterpret_cast<const short8*>(vbase + jt * jstep + vstart);
    short8 vf1 = *reinterpret_cast<const short8*>(vbase + jt * jstep + vstart + 16);

    f32x16 st = __builtin_amdgcn_mfma_f32_32x32x16_bf16(kf, qf, zacc, 0, 0, 0);

    float p[16];
#pragma unroll
    for (int r = 0; r < 16; ++r)
      p[r] = exp2f(fmaf(st[r], LOG2E, C0EXP));   // exp(st-8)

    uint x0, x1, y0, y1;
    asm("v_cvt_pk_bf16_f32 %0, %1, %2" : "=v"(x0) : "v"(p[0]), "v"(p[1]));
    asm("v_cvt_pk_bf16_f32 %0, %1, %2" : "=v"(x1) : "v"(p[2]), "v"(p[3]));
    asm("v_cvt_pk_bf16_f32 %0, %1, %2" : "=v"(y0) : "v"(p[4]), "v"(p[5]));
    asm("v_cvt_pk_bf16_f32 %0, %1, %2" : "=v"(y1) : "v"(p[6]), "v"(p[7]));
    asm("v_permlane32_swap_b32 %0, %1" : "+v"(x0), "+v"(y0));
    asm("v_permlane32_swap_b32 %0, %1" : "+v"(x1), "+v"(y1));
    union { uint u[4]; short8 s; } pa0;
    pa0.u[0] = x0; pa0.u[1] = x1; pa0.u[2] = y0; pa0.u[3] = y1;

    uint z0, z1, w0, w1;
    asm("v_cvt_pk_bf16_f32 %0, %1, %2" : "=v"(z0) : "v"(p[8]), "v"(p[9]));
    asm("v_cvt_pk_bf16_f32 %0, %1, %2" : "=v"(z1) : "v"(p[10]), "v"(p[11]));
    asm("v_cvt_pk_bf16_f32 %0, %1, %2" : "=v"(w0) : "v"(p[12]), "v"(p[13]));
    asm("v_cvt_pk_bf16_f32 %0, %1, %2" : "=v"(w1) : "v"(p[14]), "v"(p[15]));
    asm("v_permlane32_swap_b32 %0, %1" : "+v"(z0), "+v"(w0));
    asm("v_permlane32_swap_b32 %0, %1" : "+v"(z1), "+v"(w1));
    union { uint u[4]; short8 s; } pa1;
    pa1.u[0] = z0; pa1.u[1] = z1; pa1.u[2] = w0; pa1.u[3] = w1;

    accO = __builtin_amdgcn_mfma_f32_32x32x16_bf16(pa0.s, vf0, accO, 0, 0, 0);
    accO = __builtin_amdgcn_mfma_f32_32x32x16_bf16(pa1.s, vf1, accO, 0, 0, 0);
    kf = kf_n;
  }

  const int h = wh & 3;
  const int w = (wh >> 2) & 7;
  const int b = (wh >> 5) & 3;
  const int e = wh >> 7;
  const size_t rowbase =
      (size_t)e * NROWS + (size_t)b * NSEQ + (size_t)w * WSZ + (size_t)qtile * 32;
  const int src = 16 + 32 * lg;          // lane holding this half's denominators

#pragma unroll
  for (int r = 0; r < 16; ++r) {
    float den = __shfl(accO[r], src);
    if (n31 < 16) {
      int i = (r & 3) + 8 * (r >> 2) + 4 * lg;
      ao[(rowbase + i) * INNER + h * DHEAD + n31] =
          accO[r] * __builtin_amdgcn_rcpf(den);
    }
  }
}

// ---------------------------------------------------------------------------
// Kernel 3: out = (ao1 + ao2) @ Wout^T + 2*bout (unchanged from r6).
// ---------------------------------------------------------------------------
#define OSTR 76
__global__ __launch_bounds__(192) void out_proj(const float* __restrict__ ao_all,
                                                const float* __restrict__ Wout,
                                                const float* __restrict__ bout,
                                                float* __restrict__ out) {
  const int tid = threadIdx.x;
  const int row0 = blockIdx.x * 64;

  __shared__ float aos[64 * OSTR];

  const float4* __restrict__ a14 = reinterpret_cast<const float4*>(ao_all);
  const float4* __restrict__ a24 = a14 + (size_t)NROWS * (INNER / 4);

  for (int idx = tid; idx < 64 * 16; idx += 192) {
    const int r = idx >> 4, k4 = idx & 15;
    float4 u = a14[(size_t)(row0 + r) * 16 + k4];
    float4 v = a24[(size_t)(row0 + r) * 16 + k4];
    float4 s;
    s.x = u.x + v.x; s.y = u.y + v.y; s.z = u.z + v.z; s.w = u.w + v.w;
    *reinterpret_cast<float4*>(aos + r * OSTR + k4 * 4) = s;
  }

  const int j = tid % 48;
  const int rq = tid / 48;

  float wreg[INNER];
#pragma unroll
  for (int k4 = 0; k4 < 16; ++k4) {
    float4 wv4 = reinterpret_cast<const float4*>(Wout + (size_t)j * INNER)[k4];
    wreg[k4 * 4 + 0] = wv4.x; wreg[k4 * 4 + 1] = wv4.y;
    wreg[k4 * 4 + 2] = wv4.z; wreg[k4 * 4 + 3] = wv4.w;
  }
  const float bj = 2.0f * bout[j];

  __syncthreads();

  for (int r16 = 0; r16 < 16; ++r16) {
    const int r = rq * 16 + r16;
    float a0 = 0.f, a1 = 0.f, a2 = 0.f, a3 = 0.f;
#pragma unroll
    for (int kk = 0; kk < 16; ++kk) {
      const int k4 = (kk + rq * 4) & 15;
      float4 av = *reinterpret_cast<const float4*>(aos + r * OSTR + k4 * 4);
      a0 = fmaf(av.x, wreg[k4 * 4 + 0], a0);
      a1 = fmaf(av.y, wreg[k4 * 4 + 1], a1);
      a2 = fmaf(av.z, wreg[k4 * 4 + 2], a2);
      a3 = fmaf(av.w, wreg[k4 * 4 + 3], a3);
    }
    out[(size_t)(row0 + r) * CDIM + j] = (a0 + a1) + (a2 + a3) + bj;
  }
}

// ---------------------------------------------------------------------------
extern "C" void kernel_launch(void* const* d_in, const int* in_sizes, int n_in,
                              void* d_out, int out_size, void* d_ws,
                              size_t ws_size, hipStream_t stream) {
  const float* x1 = (const float*)d_in[0];
  const float* x2 = (const float*)d_in[1];
  const float* Wqkv = (const float*)d_in[2];
  const float* Wout = (const float*)d_in[3];
  const float* bout = (const float*)d_in[4];
  float* out = (float*)d_out;
  ushort* wsq = (ushort*)d_ws;
  float* ao = (float*)(wsq + QKV_TOTAL);

  qkv_mfma<<<dim3(800), dim3(256), 0, stream>>>(x1, x2, Wqkv, wsq);
  attn_mfma<<<dim3(1280), dim3(320), 0, stream>>>(wsq, ao);
  out_proj<<<dim3(400), dim3(192), 0, stream>>>(ao, Wout, bout, out);
}

// Round 8
// 69.300 us; speedup vs baseline: 1.3425x; 1.3332x over previous
//
#include <hip/hip_runtime.h>
#include <cstddef>

typedef __attribute__((ext_vector_type(8))) short short8;
typedef __attribute__((ext_vector_type(16))) float f32x16;

#define NB 4
#define NSEQ 6400
#define CDIM 48
#define DHEAD 16
#define WSZ 800
#define NWIN 8
#define INNER 64
#define NROWS 25600
#define NWH 256                       // 2*NB*NWIN*NHEADS window-heads
#define SCHUNK (WSZ * DHEAD)          // 12800
#define CHUNK (3 * SCHUNK)            // 38400 bf16 per (e,b,w,h)
#define QKV_TOTAL (NWH * CHUNK)
#define AO_PER (NROWS * INNER)

static __device__ __forceinline__ uint pkbf(float a, float b) {
  uint r;
  asm("v_cvt_pk_bf16_f32 %0, %1, %2" : "=v"(r) : "v"(a), "v"(b));
  return r;
}

// ---------------------------------------------------------------------------
// Kernel 1: QKV projection via MFMA, C^T formulation (r6 version, 18-frag W).
// ---------------------------------------------------------------------------
__global__ __launch_bounds__(256) void qkv_mfma(const float* __restrict__ x1,
                                                const float* __restrict__ x2,
                                                const float* __restrict__ Wqkv,
                                                ushort* __restrict__ wsq) {
  const int tid = threadIdx.x;
  const int lane = tid & 63;
  const int wv = tid >> 6;

  __shared__ __align__(16) ushort Wl[18 * 64 * 8];   // 18.4 KB, frag order

  for (int slot = tid; slot < 1152; slot += 256) {
    const int mtks = slot >> 6, l2 = slot & 63;
    const int mt = mtks / 3, ks = mtks % 3;
    const int o = mt * 32 + (l2 & 31);
    const int c0 = ks * 16 + (l2 >> 5) * 8;
    const float sc = ((o % CDIM) < DHEAD) ? 0.25f : 1.0f;   // fold attn scale
    const float4* p = reinterpret_cast<const float4*>(Wqkv + (size_t)o * CDIM + c0);
    float4 u = p[0], v = p[1];
    union { uint q[4]; short8 s; } t;
    t.q[0] = pkbf(u.x * sc, u.y * sc); t.q[1] = pkbf(u.z * sc, u.w * sc);
    t.q[2] = pkbf(v.x * sc, v.y * sc); t.q[3] = pkbf(v.z * sc, v.w * sc);
    *reinterpret_cast<short8*>(Wl + (size_t)slot * 8) = t.s;
  }
  __syncthreads();

  const int task = blockIdx.x * 4 + wv;   // [0,3200)
  const int batch = task >> 1;
  const int mh = task & 1;
  const int e = batch / 800;
  const int rb = (batch % 800) * 32;
  const float* __restrict__ x = e ? x2 : x1;

  const int rl = lane & 31;
  const int lg = lane >> 5;
  const int row = rb + rl;

  short8 bf[3];
#pragma unroll
  for (int ks = 0; ks < 3; ++ks) {
    const float4* p =
        reinterpret_cast<const float4*>(x + (size_t)row * CDIM + ks * 16 + lg * 8);
    float4 u = p[0], v = p[1];
    union { uint q[4]; short8 s; } t;
    t.q[0] = pkbf(u.x, u.y); t.q[1] = pkbf(u.z, u.w);
    t.q[2] = pkbf(v.x, v.y); t.q[3] = pkbf(v.z, v.w);
    bf[ks] = t.s;
  }

  const int b = rb / NSEQ;
  const int i0 = rb % NSEQ;
  const int wi = i0 / WSZ;
  const int iw = (i0 % WSZ) + rl;
  const int whb = ((e * NB + b) * NWIN + wi) * 4;

#pragma unroll
  for (int mt = mh * 3; mt < mh * 3 + 3; ++mt) {
    const int obase = mt * 32;
    short8 wf0 = *reinterpret_cast<const short8*>(Wl + ((mt * 3 + 0) * 64 + lane) * 8);
    short8 wf1 = *reinterpret_cast<const short8*>(Wl + ((mt * 3 + 1) * 64 + lane) * 8);
    short8 wf2 = *reinterpret_cast<const short8*>(Wl + ((mt * 3 + 2) * 64 + lane) * 8);

    f32x16 acc;
#pragma unroll
    for (int r = 0; r < 16; ++r) acc[r] = 0.f;
    acc = __builtin_amdgcn_mfma_f32_32x32x16_bf16(wf0, bf[0], acc, 0, 0, 0);
    acc = __builtin_amdgcn_mfma_f32_32x32x16_bf16(wf1, bf[1], acc, 0, 0, 0);
    acc = __builtin_amdgcn_mfma_f32_32x32x16_bf16(wf2, bf[2], acc, 0, 0, 0);

#pragma unroll
    for (int q = 0; q < 4; ++q) {
      const int ob = obase + q * 8 + 4 * lg;
      const int g = ob >> 4;
      const int h = g / 3, s = g % 3, d0 = ob & 15;
      uint2 pk;
      pk.x = pkbf(acc[4 * q + 0], acc[4 * q + 1]);
      pk.y = pkbf(acc[4 * q + 2], acc[4 * q + 3]);
      *reinterpret_cast<uint2*>(wsq + (size_t)(whb + h) * CHUNK + s * SCHUNK +
                                iw * DHEAD + d0) = pk;
    }
  }
}

// ---------------------------------------------------------------------------
// Kernel 2: MFMA windowed attention — VERBATIM round-4-benched version.
// j-tiled double-buffered LDS (JC=160), __expf softmax (native v_mul+v_exp),
// no setprio, no V-hoist.  Ones-column denominator in accO col 16.
// ---------------------------------------------------------------------------
#define JC 160
#define NCH 5
#define KSL (5 * 64 * 8)
#define VROW 168
#define VSL (17 * VROW)

__global__ __launch_bounds__(320) void attn_mfma(const ushort* __restrict__ wsq,
                                                 float* __restrict__ ao) {
  const int tid = threadIdx.x;
  const int lane = tid & 63;
  const int wv = tid >> 6;
  const int bid = blockIdx.x;
  const int wh = bid & (NWH - 1);
  const int sub = bid >> 8;
  const int qtile = sub * 5 + wv;        // 0..24

  const ushort* __restrict__ Qg = wsq + (size_t)wh * CHUNK;
  const ushort* __restrict__ Kg = Qg + SCHUNK;
  const ushort* __restrict__ Vg = Kg + SCHUNK;

  __shared__ __align__(16) ushort Ks[2][KSL];
  __shared__ __align__(16) ushort Vs[2][VSL];

  const int kj = (tid >> 6) * 32 + (tid & 31);
  const int khalf = (tid >> 5) & 1;
  const int vj = tid % 160;
  const int vhalf = tid / 160;

  short8 kreg = *reinterpret_cast<const short8*>(Kg + (size_t)kj * DHEAD + khalf * 8);
  short8 vreg = *reinterpret_cast<const short8*>(Vg + (size_t)vj * DHEAD + vhalf * 8);

  if (tid < JC) {
    Vs[0][16 * VROW + tid] = 0x3F80;
    Vs[1][16 * VROW + tid] = 0x3F80;
  }

  *reinterpret_cast<short8*>(&Ks[0][tid * 8]) = kreg;
#pragma unroll
  for (int u = 0; u < 8; ++u)
    Vs[0][(vhalf * 8 + u) * VROW + vj] = (ushort)vreg[u];

  kreg = *reinterpret_cast<const short8*>(Kg + (size_t)(JC + kj) * DHEAD + khalf * 8);
  vreg = *reinterpret_cast<const short8*>(Vg + (size_t)(JC + vj) * DHEAD + vhalf * 8);

  short8 qf = *reinterpret_cast<const short8*>(
      Qg + (size_t)(qtile * 32 + (lane & 31)) * DHEAD + (lane >> 5) * 8);

  __syncthreads();

  f32x16 zacc;
#pragma unroll
  for (int r = 0; r < 16; ++r) zacc[r] = 0.f;
  f32x16 accO = zacc;

  const int n31 = lane & 31;
  const int lg = lane >> 5;
  const int vrow = (n31 <= 16) ? n31 : (n31 & 15);   // col 16 -> ones row

  for (int ch = 0; ch < NCH; ++ch) {
    const ushort* __restrict__ Kc = Ks[ch & 1];
    const ushort* __restrict__ Vc = Vs[ch & 1];
#pragma unroll
    for (int jl = 0; jl < 5; ++jl) {
      short8 kf = *reinterpret_cast<const short8*>(Kc + (jl * 64 + lane) * 8);
      f32x16 st = __builtin_amdgcn_mfma_f32_32x32x16_bf16(kf, qf, zacc, 0, 0, 0);

      float p[16];
#pragma unroll
      for (int r = 0; r < 16; ++r) p[r] = __expf(st[r] - 8.0f);

      uint x0, x1, y0, y1;
      asm("v_cvt_pk_bf16_f32 %0, %1, %2" : "=v"(x0) : "v"(p[0]), "v"(p[1]));
      asm("v_cvt_pk_bf16_f32 %0, %1, %2" : "=v"(x1) : "v"(p[2]), "v"(p[3]));
      asm("v_cvt_pk_bf16_f32 %0, %1, %2" : "=v"(y0) : "v"(p[4]), "v"(p[5]));
      asm("v_cvt_pk_bf16_f32 %0, %1, %2" : "=v"(y1) : "v"(p[6]), "v"(p[7]));
      asm("v_permlane32_swap_b32 %0, %1" : "+v"(x0), "+v"(y0));
      asm("v_permlane32_swap_b32 %0, %1" : "+v"(x1), "+v"(y1));
      union { uint u[4]; short8 s; } pa0;
      pa0.u[0] = x0; pa0.u[1] = x1; pa0.u[2] = y0; pa0.u[3] = y1;

      uint z0, z1, w0, w1;
      asm("v_cvt_pk_bf16_f32 %0, %1, %2" : "=v"(z0) : "v"(p[8]), "v"(p[9]));
      asm("v_cvt_pk_bf16_f32 %0, %1, %2" : "=v"(z1) : "v"(p[10]), "v"(p[11]));
      asm("v_cvt_pk_bf16_f32 %0, %1, %2" : "=v"(w0) : "v"(p[12]), "v"(p[13]));
      asm("v_cvt_pk_bf16_f32 %0, %1, %2" : "=v"(w1) : "v"(p[14]), "v"(p[15]));
      asm("v_permlane32_swap_b32 %0, %1" : "+v"(z0), "+v"(w0));
      asm("v_permlane32_swap_b32 %0, %1" : "+v"(z1), "+v"(w1));
      union { uint u[4]; short8 s; } pa1;
      pa1.u[0] = z0; pa1.u[1] = z1; pa1.u[2] = w0; pa1.u[3] = w1;

      short8 vf0 = *reinterpret_cast<const short8*>(Vc + vrow * VROW + jl * 32 + lg * 8);
      short8 vf1 = *reinterpret_cast<const short8*>(Vc + vrow * VROW + jl * 32 + 16 + lg * 8);

      accO = __builtin_amdgcn_mfma_f32_32x32x16_bf16(pa0.s, vf0, accO, 0, 0, 0);
      accO = __builtin_amdgcn_mfma_f32_32x32x16_bf16(pa1.s, vf1, accO, 0, 0, 0);
    }
    if (ch + 1 < NCH) {
      __syncthreads();
      const int nxt = (ch + 1) & 1;
      *reinterpret_cast<short8*>(&Ks[nxt][tid * 8]) = kreg;
#pragma unroll
      for (int u = 0; u < 8; ++u)
        Vs[nxt][(vhalf * 8 + u) * VROW + vj] = (ushort)vreg[u];
      if (ch + 2 < NCH) {
        kreg = *reinterpret_cast<const short8*>(
            Kg + (size_t)((ch + 2) * JC + kj) * DHEAD + khalf * 8);
        vreg = *reinterpret_cast<const short8*>(
            Vg + (size_t)((ch + 2) * JC + vj) * DHEAD + vhalf * 8);
      }
      __syncthreads();
    }
  }

  const int h = wh & 3;
  const int w = (wh >> 2) & 7;
  const int b = (wh >> 5) & 3;
  const int e = wh >> 7;
  const size_t rowbase =
      (size_t)e * NROWS + (size_t)b * NSEQ + (size_t)w * WSZ + (size_t)qtile * 32;
  const int src = 16 + 32 * lg;

#pragma unroll
  for (int r = 0; r < 16; ++r) {
    float den = __shfl(accO[r], src);
    if (n31 < 16) {
      int i = (r & 3) + 8 * (r >> 2) + 4 * lg;
      ao[(rowbase + i) * INNER + h * DHEAD + n31] =
          accO[r] * __builtin_amdgcn_rcpf(den);
    }
  }
}

// ---------------------------------------------------------------------------
// Kernel 3: out = (ao1 + ao2) @ Wout^T + 2*bout (unchanged from r6).
// ---------------------------------------------------------------------------
#define OSTR 76
__global__ __launch_bounds__(192) void out_proj(const float* __restrict__ ao_all,
                                                const float* __restrict__ Wout,
                                                const float* __restrict__ bout,
                                                float* __restrict__ out) {
  const int tid = threadIdx.x;
  const int row0 = blockIdx.x * 64;

  __shared__ float aos[64 * OSTR];

  const float4* __restrict__ a14 = reinterpret_cast<const float4*>(ao_all);
  const float4* __restrict__ a24 = a14 + (size_t)NROWS * (INNER / 4);

  for (int idx = tid; idx < 64 * 16; idx += 192) {
    const int r = idx >> 4, k4 = idx & 15;
    float4 u = a14[(size_t)(row0 + r) * 16 + k4];
    float4 v = a24[(size_t)(row0 + r) * 16 + k4];
    float4 s;
    s.x = u.x + v.x; s.y = u.y + v.y; s.z = u.z + v.z; s.w = u.w + v.w;
    *reinterpret_cast<float4*>(aos + r * OSTR + k4 * 4) = s;
  }

  const int j = tid % 48;
  const int rq = tid / 48;

  float wreg[INNER];
#pragma unroll
  for (int k4 = 0; k4 < 16; ++k4) {
    float4 wv4 = reinterpret_cast<const float4*>(Wout + (size_t)j * INNER)[k4];
    wreg[k4 * 4 + 0] = wv4.x; wreg[k4 * 4 + 1] = wv4.y;
    wreg[k4 * 4 + 2] = wv4.z; wreg[k4 * 4 + 3] = wv4.w;
  }
  const float bj = 2.0f * bout[j];

  __syncthreads();

  for (int r16 = 0; r16 < 16; ++r16) {
    const int r = rq * 16 + r16;
    float a0 = 0.f, a1 = 0.f, a2 = 0.f, a3 = 0.f;
#pragma unroll
    for (int kk = 0; kk < 16; ++kk) {
      const int k4 = (kk + rq * 4) & 15;
      float4 av = *reinterpret_cast<const float4*>(aos + r * OSTR + k4 * 4);
      a0 = fmaf(av.x, wreg[k4 * 4 + 0], a0);
      a1 = fmaf(av.y, wreg[k4 * 4 + 1], a1);
      a2 = fmaf(av.z, wreg[k4 * 4 + 2], a2);
      a3 = fmaf(av.w, wreg[k4 * 4 + 3], a3);
    }
    out[(size_t)(row0 + r) * CDIM + j] = (a0 + a1) + (a2 + a3) + bj;
  }
}

// ---------------------------------------------------------------------------
extern "C" void kernel_launch(void* const* d_in, const int* in_sizes, int n_in,
                              void* d_out, int out_size, void* d_ws,
                              size_t ws_size, hipStream_t stream) {
  const float* x1 = (const float*)d_in[0];
  const float* x2 = (const float*)d_in[1];
  const float* Wqkv = (const float*)d_in[2];
  const float* Wout = (const float*)d_in[3];
  const float* bout = (const float*)d_in[4];
  float* out = (float*)d_out;
  ushort* wsq = (ushort*)d_ws;
  float* ao = (float*)(wsq + QKV_TOTAL);

  qkv_mfma<<<dim3(800), dim3(256), 0, stream>>>(x1, x2, Wqkv, wsq);
  attn_mfma<<<dim3(1280), dim3(320), 0, stream>>>(wsq, ao);
  out_proj<<<dim3(400), dim3(192), 0, stream>>>(ao, Wout, bout, out);
}

// Round 11
// 66.381 us; speedup vs baseline: 1.4016x; 1.0440x over previous
//
#include <hip/hip_runtime.h>
#include <cstddef>

typedef __attribute__((ext_vector_type(8))) short short8;
typedef __attribute__((ext_vector_type(16))) float f32x16;

#define NB 4
#define NSEQ 6400
#define CDIM 48
#define DHEAD 16
#define WSZ 800
#define NWIN 8
#define INNER 64
#define NROWS 25600
#define NWH 256                       // 2*NB*NWIN*NHEADS window-heads
#define SCHUNK (WSZ * DHEAD)          // 12800
#define CHUNK (3 * SCHUNK)            // 38400 bf16 per (e,b,w,h)
#define QKV_TOTAL (NWH * CHUNK)
#define AO_PER (NROWS * INNER)

static __device__ __forceinline__ uint pkbf(float a, float b) {
  uint r;
  asm("v_cvt_pk_bf16_f32 %0, %1, %2" : "=v"(r) : "v"(a), "v"(b));
  return r;
}

// ---------------------------------------------------------------------------
// Kernel 1: QKV projection via MFMA, C^T formulation.
// r8 structure + coalesced-store fix: the old path stored 4x8B per lane at
// 32B stride (25% line efficiency ~ 79MB effective writes).  Now each wave
// stages its 96x32 output tile in PRIVATE LDS ([iw][d] order, 6KB/wave,
// no barrier -- lgkmcnt ordering only) and stores 6 fully-coalesced 1KB runs.
// ---------------------------------------------------------------------------
__global__ __launch_bounds__(256) void qkv_mfma(const float* __restrict__ x1,
                                                const float* __restrict__ x2,
                                                const float* __restrict__ Wqkv,
                                                ushort* __restrict__ wsq) {
  const int tid = threadIdx.x;
  const int lane = tid & 63;
  const int wv = tid >> 6;

  __shared__ __align__(16) ushort Wl[18 * 64 * 8];   // 18.4 KB, frag order
  __shared__ __align__(16) ushort Obuf[4][6 * 512];  // 6KB per wave

  for (int slot = tid; slot < 1152; slot += 256) {
    const int mtks = slot >> 6, l2 = slot & 63;
    const int mt = mtks / 3, ks = mtks % 3;
    const int o = mt * 32 + (l2 & 31);
    const int c0 = ks * 16 + (l2 >> 5) * 8;
    const float sc = ((o % CDIM) < DHEAD) ? 0.25f : 1.0f;   // fold attn scale
    const float4* p = reinterpret_cast<const float4*>(Wqkv + (size_t)o * CDIM + c0);
    float4 u = p[0], v = p[1];
    union { uint q[4]; short8 s; } t;
    t.q[0] = pkbf(u.x * sc, u.y * sc); t.q[1] = pkbf(u.z * sc, u.w * sc);
    t.q[2] = pkbf(v.x * sc, v.y * sc); t.q[3] = pkbf(v.z * sc, v.w * sc);
    *reinterpret_cast<short8*>(Wl + (size_t)slot * 8) = t.s;
  }
  __syncthreads();

  const int task = blockIdx.x * 4 + wv;   // [0,3200)
  const int batch = task >> 1;
  const int mh = task & 1;
  const int e = batch / 800;
  const int rb = (batch % 800) * 32;
  const float* __restrict__ x = e ? x2 : x1;

  const int rl = lane & 31;
  const int lg = lane >> 5;
  const int row = rb + rl;

  short8 bf[3];
#pragma unroll
  for (int ks = 0; ks < 3; ++ks) {
    const float4* p =
        reinterpret_cast<const float4*>(x + (size_t)row * CDIM + ks * 16 + lg * 8);
    float4 u = p[0], v = p[1];
    union { uint q[4]; short8 s; } t;
    t.q[0] = pkbf(u.x, u.y); t.q[1] = pkbf(u.z, u.w);
    t.q[2] = pkbf(v.x, v.y); t.q[3] = pkbf(v.z, v.w);
    bf[ks] = t.s;
  }

  const int b = rb / NSEQ;
  const int i0 = rb % NSEQ;
  const int wi = i0 / WSZ;
  const int iwb = i0 % WSZ;              // window-local base row (800%32==0)
  const int whb = ((e * NB + b) * NWIN + wi) * 4;

#pragma unroll
  for (int mt = mh * 3; mt < mh * 3 + 3; ++mt) {
    const int obase = mt * 32;
    short8 wf0 = *reinterpret_cast<const short8*>(Wl + ((mt * 3 + 0) * 64 + lane) * 8);
    short8 wf1 = *reinterpret_cast<const short8*>(Wl + ((mt * 3 + 1) * 64 + lane) * 8);
    short8 wf2 = *reinterpret_cast<const short8*>(Wl + ((mt * 3 + 2) * 64 + lane) * 8);

    f32x16 acc;
#pragma unroll
    for (int r = 0; r < 16; ++r) acc[r] = 0.f;
    acc = __builtin_amdgcn_mfma_f32_32x32x16_bf16(wf0, bf[0], acc, 0, 0, 0);
    acc = __builtin_amdgcn_mfma_f32_32x32x16_bf16(wf1, bf[1], acc, 0, 0, 0);
    acc = __builtin_amdgcn_mfma_f32_32x32x16_bf16(wf2, bf[2], acc, 0, 0, 0);

    // D reg 4q+k: o' = obase + q*8 + 4*lg + k, row' = rb + (lane&31).
    // Stage to LDS [group g2 = (o'-mh*96)>>4][iw = lane&31][d0 = o'&15]
#pragma unroll
    for (int q = 0; q < 4; ++q) {
      const int op = obase + q * 8 + 4 * lg - mh * 96;   // 0..95
      const int g2 = op >> 4;                            // 0..5
      const int d0 = op & 15;
      uint2 pk;
      pk.x = pkbf(acc[4 * q + 0], acc[4 * q + 1]);
      pk.y = pkbf(acc[4 * q + 2], acc[4 * q + 3]);
      *reinterpret_cast<uint2*>(&Obuf[wv][g2 * 512 + rl * 16 + d0]) = pk;
    }
  }

  // coalesced store: 6 groups x 1KB; LDS [iw][d] maps linearly to global.
#pragma unroll
  for (int g2 = 0; g2 < 6; ++g2) {
    const int g = mh * 6 + g2;           // global 16-o group
    const int h = g / 3, s = g % 3;
    short8 val = *reinterpret_cast<const short8*>(&Obuf[wv][g2 * 512 + lane * 8]);
    *reinterpret_cast<short8*>(wsq + (size_t)(whb + h) * CHUNK + s * SCHUNK +
                               (size_t)iwb * DHEAD + lane * 8) = val;
  }
}

// ---------------------------------------------------------------------------
// Kernel 2: MFMA windowed attention — r8 chunked structure (proven), with
// one change: the -8 softmax shift is folded into the QK^T accumulator init
// (C_in = -8 -> MFMA emits s-8 directly; deletes 16 v_sub per jt).
// ---------------------------------------------------------------------------
#define JC 160
#define NCH 5
#define KSL (5 * 64 * 8)
#define VROW 168
#define VSL (17 * VROW)

__global__ __launch_bounds__(320) void attn_mfma(const ushort* __restrict__ wsq,
                                                 float* __restrict__ ao) {
  const int tid = threadIdx.x;
  const int lane = tid & 63;
  const int wv = tid >> 6;
  const int bid = blockIdx.x;
  const int wh = bid & (NWH - 1);
  const int sub = bid >> 8;
  const int qtile = sub * 5 + wv;        // 0..24

  const ushort* __restrict__ Qg = wsq + (size_t)wh * CHUNK;
  const ushort* __restrict__ Kg = Qg + SCHUNK;
  const ushort* __restrict__ Vg = Kg + SCHUNK;

  __shared__ __align__(16) ushort Ks[2][KSL];
  __shared__ __align__(16) ushort Vs[2][VSL];

  const int kj = (tid >> 6) * 32 + (tid & 31);
  const int khalf = (tid >> 5) & 1;
  const int vj = tid % 160;
  const int vhalf = tid / 160;

  short8 kreg = *reinterpret_cast<const short8*>(Kg + (size_t)kj * DHEAD + khalf * 8);
  short8 vreg = *reinterpret_cast<const short8*>(Vg + (size_t)vj * DHEAD + vhalf * 8);

  if (tid < JC) {
    Vs[0][16 * VROW + tid] = 0x3F80;
    Vs[1][16 * VROW + tid] = 0x3F80;
  }

  *reinterpret_cast<short8*>(&Ks[0][tid * 8]) = kreg;
#pragma unroll
  for (int u = 0; u < 8; ++u)
    Vs[0][(vhalf * 8 + u) * VROW + vj] = (ushort)vreg[u];

  kreg = *reinterpret_cast<const short8*>(Kg + (size_t)(JC + kj) * DHEAD + khalf * 8);
  vreg = *reinterpret_cast<const short8*>(Vg + (size_t)(JC + vj) * DHEAD + vhalf * 8);

  short8 qf = *reinterpret_cast<const short8*>(
      Qg + (size_t)(qtile * 32 + (lane & 31)) * DHEAD + (lane >> 5) * 8);

  __syncthreads();

  f32x16 sinit;
#pragma unroll
  for (int r = 0; r < 16; ++r) sinit[r] = -8.0f;   // softmax shift via C-in
  f32x16 accO;
#pragma unroll
  for (int r = 0; r < 16; ++r) accO[r] = 0.f;

  const int n31 = lane & 31;
  const int lg = lane >> 5;
  const int vrow = (n31 <= 16) ? n31 : (n31 & 15);   // col 16 -> ones row

  for (int ch = 0; ch < NCH; ++ch) {
    const ushort* __restrict__ Kc = Ks[ch & 1];
    const ushort* __restrict__ Vc = Vs[ch & 1];
#pragma unroll
    for (int jl = 0; jl < 5; ++jl) {
      short8 kf = *reinterpret_cast<const short8*>(Kc + (jl * 64 + lane) * 8);
      f32x16 st = __builtin_amdgcn_mfma_f32_32x32x16_bf16(kf, qf, sinit, 0, 0, 0);

      float p[16];
#pragma unroll
      for (int r = 0; r < 16; ++r) p[r] = __expf(st[r]);   // exp(s-8)

      uint x0, x1, y0, y1;
      asm("v_cvt_pk_bf16_f32 %0, %1, %2" : "=v"(x0) : "v"(p[0]), "v"(p[1]));
      asm("v_cvt_pk_bf16_f32 %0, %1, %2" : "=v"(x1) : "v"(p[2]), "v"(p[3]));
      asm("v_cvt_pk_bf16_f32 %0, %1, %2" : "=v"(y0) : "v"(p[4]), "v"(p[5]));
      asm("v_cvt_pk_bf16_f32 %0, %1, %2" : "=v"(y1) : "v"(p[6]), "v"(p[7]));
      asm("v_permlane32_swap_b32 %0, %1" : "+v"(x0), "+v"(y0));
      asm("v_permlane32_swap_b32 %0, %1" : "+v"(x1), "+v"(y1));
      union { uint u[4]; short8 s; } pa0;
      pa0.u[0] = x0; pa0.u[1] = x1; pa0.u[2] = y0; pa0.u[3] = y1;

      uint z0, z1, w0, w1;
      asm("v_cvt_pk_bf16_f32 %0, %1, %2" : "=v"(z0) : "v"(p[8]), "v"(p[9]));
      asm("v_cvt_pk_bf16_f32 %0, %1, %2" : "=v"(z1) : "v"(p[10]), "v"(p[11]));
      asm("v_cvt_pk_bf16_f32 %0, %1, %2" : "=v"(w0) : "v"(p[12]), "v"(p[13]));
      asm("v_cvt_pk_bf16_f32 %0, %1, %2" : "=v"(w1) : "v"(p[14]), "v"(p[15]));
      asm("v_permlane32_swap_b32 %0, %1" : "+v"(z0), "+v"(w0));
      asm("v_permlane32_swap_b32 %0, %1" : "+v"(z1), "+v"(w1));
      union { uint u[4]; short8 s; } pa1;
      pa1.u[0] = z0; pa1.u[1] = z1; pa1.u[2] = w0; pa1.u[3] = w1;

      short8 vf0 = *reinterpret_cast<const short8*>(Vc + vrow * VROW + jl * 32 + lg * 8);
      short8 vf1 = *reinterpret_cast<const short8*>(Vc + vrow * VROW + jl * 32 + 16 + lg * 8);

      accO = __builtin_amdgcn_mfma_f32_32x32x16_bf16(pa0.s, vf0, accO, 0, 0, 0);
      accO = __builtin_amdgcn_mfma_f32_32x32x16_bf16(pa1.s, vf1, accO, 0, 0, 0);
    }
    if (ch + 1 < NCH) {
      __syncthreads();
      const int nxt = (ch + 1) & 1;
      *reinterpret_cast<short8*>(&Ks[nxt][tid * 8]) = kreg;
#pragma unroll
      for (int u = 0; u < 8; ++u)
        Vs[nxt][(vhalf * 8 + u) * VROW + vj] = (ushort)vreg[u];
      if (ch + 2 < NCH) {
        kreg = *reinterpret_cast<const short8*>(
            Kg + (size_t)((ch + 2) * JC + kj) * DHEAD + khalf * 8);
        vreg = *reinterpret_cast<const short8*>(
            Vg + (size_t)((ch + 2) * JC + vj) * DHEAD + vhalf * 8);
      }
      __syncthreads();
    }
  }

  const int h = wh & 3;
  const int w = (wh >> 2) & 7;
  const int b = (wh >> 5) & 3;
  const int e = wh >> 7;
  const size_t rowbase =
      (size_t)e * NROWS + (size_t)b * NSEQ + (size_t)w * WSZ + (size_t)qtile * 32;
  const int src = 16 + 32 * lg;

#pragma unroll
  for (int r = 0; r < 16; ++r) {
    float den = __shfl(accO[r], src);
    if (n31 < 16) {
      int i = (r & 3) + 8 * (r >> 2) + 4 * lg;
      ao[(rowbase + i) * INNER + h * DHEAD + n31] =
          accO[r] * __builtin_amdgcn_rcpf(den);
    }
  }
}

// ---------------------------------------------------------------------------
// Kernel 3: out = (ao1 + ao2) @ Wout^T + 2*bout (unchanged from r8).
// ---------------------------------------------------------------------------
#define OSTR 76
__global__ __launch_bounds__(192) void out_proj(const float* __restrict__ ao_all,
                                                const float* __restrict__ Wout,
                                                const float* __restrict__ bout,
                                                float* __restrict__ out) {
  const int tid = threadIdx.x;
  const int row0 = blockIdx.x * 64;

  __shared__ float aos[64 * OSTR];

  const float4* __restrict__ a14 = reinterpret_cast<const float4*>(ao_all);
  const float4* __restrict__ a24 = a14 + (size_t)NROWS * (INNER / 4);

  for (int idx = tid; idx < 64 * 16; idx += 192) {
    const int r = idx >> 4, k4 = idx & 15;
    float4 u = a14[(size_t)(row0 + r) * 16 + k4];
    float4 v = a24[(size_t)(row0 + r) * 16 + k4];
    float4 s;
    s.x = u.x + v.x; s.y = u.y + v.y; s.z = u.z + v.z; s.w = u.w + v.w;
    *reinterpret_cast<float4*>(aos + r * OSTR + k4 * 4) = s;
  }

  const int j = tid % 48;
  const int rq = tid / 48;

  float wreg[INNER];
#pragma unroll
  for (int k4 = 0; k4 < 16; ++k4) {
    float4 wv4 = reinterpret_cast<const float4*>(Wout + (size_t)j * INNER)[k4];
    wreg[k4 * 4 + 0] = wv4.x; wreg[k4 * 4 + 1] = wv4.y;
    wreg[k4 * 4 + 2] = wv4.z; wreg[k4 * 4 + 3] = wv4.w;
  }
  const float bj = 2.0f * bout[j];

  __syncthreads();

  for (int r16 = 0; r16 < 16; ++r16) {
    const int r = rq * 16 + r16;
    float a0 = 0.f, a1 = 0.f, a2 = 0.f, a3 = 0.f;
#pragma unroll
    for (int kk = 0; kk < 16; ++kk) {
      const int k4 = (kk + rq * 4) & 15;
      float4 av = *reinterpret_cast<const float4*>(aos + r * OSTR + k4 * 4);
      a0 = fmaf(av.x, wreg[k4 * 4 + 0], a0);
      a1 = fmaf(av.y, wreg[k4 * 4 + 1], a1);
      a2 = fmaf(av.z, wreg[k4 * 4 + 2], a2);
      a3 = fmaf(av.w, wreg[k4 * 4 + 3], a3);
    }
    out[(size_t)(row0 + r) * CDIM + j] = (a0 + a1) + (a2 + a3) + bj;
  }
}

// ---------------------------------------------------------------------------
extern "C" void kernel_launch(void* const* d_in, const int* in_sizes, int n_in,
                              void* d_out, int out_size, void* d_ws,
                              size_t ws_size, hipStream_t stream) {
  const float* x1 = (const float*)d_in[0];
  const float* x2 = (const float*)d_in[1];
  const float* Wqkv = (const float*)d_in[2];
  const float* Wout = (const float*)d_in[3];
  const float* bout = (const float*)d_in[4];
  float* out = (float*)d_out;
  ushort* wsq = (ushort*)d_ws;
  float* ao = (float*)(wsq + QKV_TOTAL);

  qkv_mfma<<<dim3(800), dim3(256), 0, stream>>>(x1, x2, Wqkv, wsq);
  attn_mfma<<<dim3(1280), dim3(320), 0, stream>>>(wsq, ao);
  out_proj<<<dim3(400), dim3(192), 0, stream>>>(ao, Wout, bout, out);
}

// Round 12
// 65.572 us; speedup vs baseline: 1.4188x; 1.0123x over previous
//
#include <hip/hip_runtime.h>
#include <cstddef>

typedef __attribute__((ext_vector_type(8))) short short8;
typedef __attribute__((ext_vector_type(16))) float f32x16;

#define NB 4
#define NSEQ 6400
#define CDIM 48
#define DHEAD 16
#define WSZ 800
#define NWIN 8
#define INNER 64
#define NROWS 25600
#define NWH 256                       // 2*NB*NWIN*NHEADS window-heads
#define SCHUNK (WSZ * DHEAD)          // 12800
#define CHUNK (3 * SCHUNK)            // 38400 bf16 per (e,b,w,h)
#define QKV_TOTAL (NWH * CHUNK)
#define AO_PER (NROWS * INNER)        // bf16 elements per input now

static __device__ __forceinline__ uint pkbf(float a, float b) {
  uint r;
  asm("v_cvt_pk_bf16_f32 %0, %1, %2" : "=v"(r) : "v"(a), "v"(b));
  return r;
}
static __device__ __forceinline__ float bf2f(ushort u) {
  return __uint_as_float(((uint)u) << 16);
}

// ---------------------------------------------------------------------------
// Kernel 1: QKV projection via MFMA, C^T formulation (unchanged from r11:
// LDS W frags + wave-private Obuf staging -> 6 coalesced 1KB stores).
// ---------------------------------------------------------------------------
__global__ __launch_bounds__(256) void qkv_mfma(const float* __restrict__ x1,
                                                const float* __restrict__ x2,
                                                const float* __restrict__ Wqkv,
                                                ushort* __restrict__ wsq) {
  const int tid = threadIdx.x;
  const int lane = tid & 63;
  const int wv = tid >> 6;

  __shared__ __align__(16) ushort Wl[18 * 64 * 8];   // 18.4 KB, frag order
  __shared__ __align__(16) ushort Obuf[4][6 * 512];  // 6KB per wave

  for (int slot = tid; slot < 1152; slot += 256) {
    const int mtks = slot >> 6, l2 = slot & 63;
    const int mt = mtks / 3, ks = mtks % 3;
    const int o = mt * 32 + (l2 & 31);
    const int c0 = ks * 16 + (l2 >> 5) * 8;
    const float sc = ((o % CDIM) < DHEAD) ? 0.25f : 1.0f;   // fold attn scale
    const float4* p = reinterpret_cast<const float4*>(Wqkv + (size_t)o * CDIM + c0);
    float4 u = p[0], v = p[1];
    union { uint q[4]; short8 s; } t;
    t.q[0] = pkbf(u.x * sc, u.y * sc); t.q[1] = pkbf(u.z * sc, u.w * sc);
    t.q[2] = pkbf(v.x * sc, v.y * sc); t.q[3] = pkbf(v.z * sc, v.w * sc);
    *reinterpret_cast<short8*>(Wl + (size_t)slot * 8) = t.s;
  }
  __syncthreads();

  const int task = blockIdx.x * 4 + wv;   // [0,3200)
  const int batch = task >> 1;
  const int mh = task & 1;
  const int e = batch / 800;
  const int rb = (batch % 800) * 32;
  const float* __restrict__ x = e ? x2 : x1;

  const int rl = lane & 31;
  const int lg = lane >> 5;
  const int row = rb + rl;

  short8 bf[3];
#pragma unroll
  for (int ks = 0; ks < 3; ++ks) {
    const float4* p =
        reinterpret_cast<const float4*>(x + (size_t)row * CDIM + ks * 16 + lg * 8);
    float4 u = p[0], v = p[1];
    union { uint q[4]; short8 s; } t;
    t.q[0] = pkbf(u.x, u.y); t.q[1] = pkbf(u.z, u.w);
    t.q[2] = pkbf(v.x, v.y); t.q[3] = pkbf(v.z, v.w);
    bf[ks] = t.s;
  }

  const int b = rb / NSEQ;
  const int i0 = rb % NSEQ;
  const int wi = i0 / WSZ;
  const int iwb = i0 % WSZ;              // window-local base row (800%32==0)
  const int whb = ((e * NB + b) * NWIN + wi) * 4;

#pragma unroll
  for (int mt = mh * 3; mt < mh * 3 + 3; ++mt) {
    const int obase = mt * 32;
    short8 wf0 = *reinterpret_cast<const short8*>(Wl + ((mt * 3 + 0) * 64 + lane) * 8);
    short8 wf1 = *reinterpret_cast<const short8*>(Wl + ((mt * 3 + 1) * 64 + lane) * 8);
    short8 wf2 = *reinterpret_cast<const short8*>(Wl + ((mt * 3 + 2) * 64 + lane) * 8);

    f32x16 acc;
#pragma unroll
    for (int r = 0; r < 16; ++r) acc[r] = 0.f;
    acc = __builtin_amdgcn_mfma_f32_32x32x16_bf16(wf0, bf[0], acc, 0, 0, 0);
    acc = __builtin_amdgcn_mfma_f32_32x32x16_bf16(wf1, bf[1], acc, 0, 0, 0);
    acc = __builtin_amdgcn_mfma_f32_32x32x16_bf16(wf2, bf[2], acc, 0, 0, 0);

#pragma unroll
    for (int q = 0; q < 4; ++q) {
      const int op = obase + q * 8 + 4 * lg - mh * 96;   // 0..95
      const int g2 = op >> 4;                            // 0..5
      const int d0 = op & 15;
      uint2 pk;
      pk.x = pkbf(acc[4 * q + 0], acc[4 * q + 1]);
      pk.y = pkbf(acc[4 * q + 2], acc[4 * q + 3]);
      *reinterpret_cast<uint2*>(&Obuf[wv][g2 * 512 + rl * 16 + d0]) = pk;
    }
  }

#pragma unroll
  for (int g2 = 0; g2 < 6; ++g2) {
    const int g = mh * 6 + g2;           // global 16-o group
    const int h = g / 3, s = g % 3;
    short8 val = *reinterpret_cast<const short8*>(&Obuf[wv][g2 * 512 + lane * 8]);
    *reinterpret_cast<short8*>(wsq + (size_t)(whb + h) * CHUNK + s * SCHUNK +
                               (size_t)iwb * DHEAD + lane * 8) = val;
  }
}

// ---------------------------------------------------------------------------
// Kernel 2: MFMA windowed attention — r11 chunked structure with:
//  * K-frags DIRECT from global (one coalesced 1KB segment per wave per jt;
//    identical lane->element mapping as the staged path; L2-hot).  Ks LDS
//    buffer deleted; barriers remain (they order the V staging, unchanged).
//  * ao written as bf16 (halves the ao round-trip).
// ---------------------------------------------------------------------------
#define JC 160
#define NCH 5
#define VROW 168
#define VSL (17 * VROW)

__global__ __launch_bounds__(320) void attn_mfma(const ushort* __restrict__ wsq,
                                                 ushort* __restrict__ ao) {
  const int tid = threadIdx.x;
  const int lane = tid & 63;
  const int wv = tid >> 6;
  const int bid = blockIdx.x;
  const int wh = bid & (NWH - 1);
  const int sub = bid >> 8;
  const int qtile = sub * 5 + wv;        // 0..24

  const ushort* __restrict__ Qg = wsq + (size_t)wh * CHUNK;
  const ushort* __restrict__ Kg = Qg + SCHUNK;
  const ushort* __restrict__ Vg = Kg + SCHUNK;

  __shared__ __align__(16) ushort Vs[2][VSL];   // 11.4 KB total

  const int vj = tid % 160;
  const int vhalf = tid / 160;

  short8 vreg = *reinterpret_cast<const short8*>(Vg + (size_t)vj * DHEAD + vhalf * 8);

  if (tid < JC) {
    Vs[0][16 * VROW + tid] = 0x3F80;
    Vs[1][16 * VROW + tid] = 0x3F80;
  }

#pragma unroll
  for (int u = 0; u < 8; ++u)
    Vs[0][(vhalf * 8 + u) * VROW + vj] = (ushort)vreg[u];

  vreg = *reinterpret_cast<const short8*>(Vg + (size_t)(JC + vj) * DHEAD + vhalf * 8);

  short8 qf = *reinterpret_cast<const short8*>(
      Qg + (size_t)(qtile * 32 + (lane & 31)) * DHEAD + (lane >> 5) * 8);

  __syncthreads();

  f32x16 sinit;
#pragma unroll
  for (int r = 0; r < 16; ++r) sinit[r] = -8.0f;   // softmax shift via C-in
  f32x16 accO;
#pragma unroll
  for (int r = 0; r < 16; ++r) accO[r] = 0.f;

  const int n31 = lane & 31;
  const int lg = lane >> 5;
  const int vrow = (n31 <= 16) ? n31 : (n31 & 15);   // col 16 -> ones row
  const ushort* __restrict__ kfb = Kg + (size_t)n31 * DHEAD + lg * 8;

  for (int ch = 0; ch < NCH; ++ch) {
    const ushort* __restrict__ Vc = Vs[ch & 1];
#pragma unroll
    for (int jl = 0; jl < 5; ++jl) {
      // K A-frag direct from global: coalesced 1KB per wave, L2-hot
      short8 kf = *reinterpret_cast<const short8*>(
          kfb + (size_t)(ch * JC + jl * 32) * DHEAD);
      f32x16 st = __builtin_amdgcn_mfma_f32_32x32x16_bf16(kf, qf, sinit, 0, 0, 0);

      float p[16];
#pragma unroll
      for (int r = 0; r < 16; ++r) p[r] = __expf(st[r]);   // exp(s-8)

      uint x0, x1, y0, y1;
      asm("v_cvt_pk_bf16_f32 %0, %1, %2" : "=v"(x0) : "v"(p[0]), "v"(p[1]));
      asm("v_cvt_pk_bf16_f32 %0, %1, %2" : "=v"(x1) : "v"(p[2]), "v"(p[3]));
      asm("v_cvt_pk_bf16_f32 %0, %1, %2" : "=v"(y0) : "v"(p[4]), "v"(p[5]));
      asm("v_cvt_pk_bf16_f32 %0, %1, %2" : "=v"(y1) : "v"(p[6]), "v"(p[7]));
      asm("v_permlane32_swap_b32 %0, %1" : "+v"(x0), "+v"(y0));
      asm("v_permlane32_swap_b32 %0, %1" : "+v"(x1), "+v"(y1));
      union { uint u[4]; short8 s; } pa0;
      pa0.u[0] = x0; pa0.u[1] = x1; pa0.u[2] = y0; pa0.u[3] = y1;

      uint z0, z1, w0, w1;
      asm("v_cvt_pk_bf16_f32 %0, %1, %2" : "=v"(z0) : "v"(p[8]), "v"(p[9]));
      asm("v_cvt_pk_bf16_f32 %0, %1, %2" : "=v"(z1) : "v"(p[10]), "v"(p[11]));
      asm("v_cvt_pk_bf16_f32 %0, %1, %2" : "=v"(w0) : "v"(p[12]), "v"(p[13]));
      asm("v_cvt_pk_bf16_f32 %0, %1, %2" : "=v"(w1) : "v"(p[14]), "v"(p[15]));
      asm("v_permlane32_swap_b32 %0, %1" : "+v"(z0), "+v"(w0));
      asm("v_permlane32_swap_b32 %0, %1" : "+v"(z1), "+v"(w1));
      union { uint u[4]; short8 s; } pa1;
      pa1.u[0] = z0; pa1.u[1] = z1; pa1.u[2] = w0; pa1.u[3] = w1;

      short8 vf0 = *reinterpret_cast<const short8*>(Vc + vrow * VROW + jl * 32 + lg * 8);
      short8 vf1 = *reinterpret_cast<const short8*>(Vc + vrow * VROW + jl * 32 + 16 + lg * 8);

      accO = __builtin_amdgcn_mfma_f32_32x32x16_bf16(pa0.s, vf0, accO, 0, 0, 0);
      accO = __builtin_amdgcn_mfma_f32_32x32x16_bf16(pa1.s, vf1, accO, 0, 0, 0);
    }
    if (ch + 1 < NCH) {
      __syncthreads();
      const int nxt = (ch + 1) & 1;
#pragma unroll
      for (int u = 0; u < 8; ++u)
        Vs[nxt][(vhalf * 8 + u) * VROW + vj] = (ushort)vreg[u];
      if (ch + 2 < NCH) {
        vreg = *reinterpret_cast<const short8*>(
            Vg + (size_t)((ch + 2) * JC + vj) * DHEAD + vhalf * 8);
      }
      __syncthreads();
    }
  }

  const int h = wh & 3;
  const int w = (wh >> 2) & 7;
  const int b = (wh >> 5) & 3;
  const int e = wh >> 7;
  const size_t rowbase =
      (size_t)e * NROWS + (size_t)b * NSEQ + (size_t)w * WSZ + (size_t)qtile * 32;
  const int src = 16 + 32 * lg;

#pragma unroll
  for (int r = 0; r < 16; ++r) {
    float den = __shfl(accO[r], src);
    if (n31 < 16) {
      int i = (r & 3) + 8 * (r >> 2) + 4 * lg;
      float val = accO[r] * __builtin_amdgcn_rcpf(den);
      ao[(rowbase + i) * INNER + h * DHEAD + n31] = (ushort)pkbf(val, val);
    }
  }
}

// ---------------------------------------------------------------------------
// Kernel 3: out = (ao1 + ao2) @ Wout^T + 2*bout.  ao now bf16 (converted on
// load, math in fp32); structure otherwise unchanged from r11.
// ---------------------------------------------------------------------------
#define OSTR 76
__global__ __launch_bounds__(192) void out_proj(const ushort* __restrict__ ao_all,
                                                const float* __restrict__ Wout,
                                                const float* __restrict__ bout,
                                                float* __restrict__ out) {
  const int tid = threadIdx.x;
  const int row0 = blockIdx.x * 64;

  __shared__ float aos[64 * OSTR];

  const ushort* __restrict__ a1 = ao_all;
  const ushort* __restrict__ a2 = ao_all + (size_t)AO_PER;

  for (int idx = tid; idx < 64 * 8; idx += 192) {
    const int r = idx >> 3, c = idx & 7;          // 8 short8-chunks per row
    const size_t g = (size_t)(row0 + r) * INNER + c * 8;
    short8 u = *reinterpret_cast<const short8*>(a1 + g);
    short8 v = *reinterpret_cast<const short8*>(a2 + g);
    float4 s0, s1;
    s0.x = bf2f((ushort)u[0]) + bf2f((ushort)v[0]);
    s0.y = bf2f((ushort)u[1]) + bf2f((ushort)v[1]);
    s0.z = bf2f((ushort)u[2]) + bf2f((ushort)v[2]);
    s0.w = bf2f((ushort)u[3]) + bf2f((ushort)v[3]);
    s1.x = bf2f((ushort)u[4]) + bf2f((ushort)v[4]);
    s1.y = bf2f((ushort)u[5]) + bf2f((ushort)v[5]);
    s1.z = bf2f((ushort)u[6]) + bf2f((ushort)v[6]);
    s1.w = bf2f((ushort)u[7]) + bf2f((ushort)v[7]);
    *reinterpret_cast<float4*>(aos + r * OSTR + c * 8) = s0;
    *reinterpret_cast<float4*>(aos + r * OSTR + c * 8 + 4) = s1;
  }

  const int j = tid % 48;
  const int rq = tid / 48;

  float wreg[INNER];
#pragma unroll
  for (int k4 = 0; k4 < 16; ++k4) {
    float4 wv4 = reinterpret_cast<const float4*>(Wout + (size_t)j * INNER)[k4];
    wreg[k4 * 4 + 0] = wv4.x; wreg[k4 * 4 + 1] = wv4.y;
    wreg[k4 * 4 + 2] = wv4.z; wreg[k4 * 4 + 3] = wv4.w;
  }
  const float bj = 2.0f * bout[j];

  __syncthreads();

  for (int r16 = 0; r16 < 16; ++r16) {
    const int r = rq * 16 + r16;
    float a0 = 0.f, a1v = 0.f, a2v = 0.f, a3 = 0.f;
#pragma unroll
    for (int kk = 0; kk < 16; ++kk) {
      const int k4 = (kk + rq * 4) & 15;
      float4 av = *reinterpret_cast<const float4*>(aos + r * OSTR + k4 * 4);
      a0 = fmaf(av.x, wreg[k4 * 4 + 0], a0);
      a1v = fmaf(av.y, wreg[k4 * 4 + 1], a1v);
      a2v = fmaf(av.z, wreg[k4 * 4 + 2], a2v);
      a3 = fmaf(av.w, wreg[k4 * 4 + 3], a3);
    }
    out[(size_t)(row0 + r) * CDIM + j] = (a0 + a1v) + (a2v + a3) + bj;
  }
}

// ---------------------------------------------------------------------------
extern "C" void kernel_launch(void* const* d_in, const int* in_sizes, int n_in,
                              void* d_out, int out_size, void* d_ws,
                              size_t ws_size, hipStream_t stream) {
  const float* x1 = (const float*)d_in[0];
  const float* x2 = (const float*)d_in[1];
  const float* Wqkv = (const float*)d_in[2];
  const float* Wout = (const float*)d_in[3];
  const float* bout = (const float*)d_in[4];
  float* out = (float*)d_out;
  ushort* wsq = (ushort*)d_ws;
  ushort* ao = wsq + QKV_TOTAL;          // bf16 region after bf16 QKV

  qkv_mfma<<<dim3(800), dim3(256), 0, stream>>>(x1, x2, Wqkv, wsq);
  attn_mfma<<<dim3(1280), dim3(320), 0, stream>>>(wsq, ao);
  out_proj<<<dim3(400), dim3(192), 0, stream>>>(ao, Wout, bout, out);
}